// Round 6
// baseline (57.025 us; speedup 1.0000x reference)
//
#include <hip/hip_runtime.h>

#define SEQ 2048
#define NH 8
#define NB 4

typedef unsigned int u32;
typedef unsigned long long u64;
typedef short bf16x8_t __attribute__((ext_vector_type(8)));
typedef float f32x16_t __attribute__((ext_vector_type(16)));

// f32 -> bf16 round-to-nearest-even, pure integer (no asm)
__device__ __forceinline__ u32 bfr(float f) {
    u32 u = __builtin_bit_cast(u32, f);
    return (u + 0x7FFFu + ((u >> 16) & 1u)) >> 16;
}
__device__ __forceinline__ u32 pkb(float a, float b) {
    return bfr(a) | (bfr(b) << 16);
}
__device__ __forceinline__ float bf2f(u32 h) {
    return __builtin_bit_cast(float, h << 16);
}
// exchange with lane^32
__device__ __forceinline__ u32 half_swap(u32 v) {
    return (u32)__shfl_xor((int)v, 32, 64);
}

union UBv { bf16x8_t v; u32 u[4]; };

__global__ __launch_bounds__(256)
void attn_mfma(const float* __restrict__ x, const float* __restrict__ Wq,
               const float* __restrict__ Wk, const float* __restrict__ Wv,
               float* __restrict__ out) {
    // XF: per-key packed bf16 {x0,x1},{x2,0} -> scores-mfma A frags (16 KB)
    // VTb: bf16 V'^T rows d=0..3 (x0,x1,x2,ones), row stride 4112 B
    // RED: cross-wave partials
    __shared__ u64 XF[SEQ];
    __shared__ __align__(16) char VTb[4 * 4112];
    __shared__ __align__(16) float RED[4][8][16];

    const int tid = threadIdx.x;
    const int blk = blockIdx.x;
    const int qb  = blk & 31;      // 64-query tile
    const int bh  = blk >> 5;
    const int h   = bh & 7;
    const int b   = bh >> 3;

    // ---- staging: 8 keys per thread ----
    {
        const float4* xg = (const float4*)(x + b * SEQ * 3);
        float xv[24];
        const float4 t0 = xg[tid * 6 + 0]; xv[0]=t0.x; xv[1]=t0.y; xv[2]=t0.z; xv[3]=t0.w;
        const float4 t1 = xg[tid * 6 + 1]; xv[4]=t1.x; xv[5]=t1.y; xv[6]=t1.z; xv[7]=t1.w;
        const float4 t2 = xg[tid * 6 + 2]; xv[8]=t2.x; xv[9]=t2.y; xv[10]=t2.z; xv[11]=t2.w;
        const float4 t3 = xg[tid * 6 + 3]; xv[12]=t3.x; xv[13]=t3.y; xv[14]=t3.z; xv[15]=t3.w;
        const float4 t4 = xg[tid * 6 + 4]; xv[16]=t4.x; xv[17]=t4.y; xv[18]=t4.z; xv[19]=t4.w;
        const float4 t5 = xg[tid * 6 + 5]; xv[20]=t5.x; xv[21]=t5.y; xv[22]=t5.z; xv[23]=t5.w;
        const int k0 = tid * 8;
#pragma unroll
        for (int j = 0; j < 8; j += 2) {
            uint4 w;
            w.x = pkb(xv[3*j + 0], xv[3*j + 1]);
            w.y = pkb(xv[3*j + 2], 0.f);
            w.z = pkb(xv[3*j + 3], xv[3*j + 4]);
            w.w = pkb(xv[3*j + 5], 0.f);
            *(uint4*)&XF[k0 + j] = w;
        }
#pragma unroll
        for (int d = 0; d < 3; ++d) {
            uint4 w;
            w.x = pkb(xv[0 + d],  xv[3 + d]);
            w.y = pkb(xv[6 + d],  xv[9 + d]);
            w.z = pkb(xv[12 + d], xv[15 + d]);
            w.w = pkb(xv[18 + d], xv[21 + d]);
            *(uint4*)(VTb + d * 4112 + k0 * 2) = w;
        }
        uint4 ones; ones.x = ones.y = ones.z = ones.w = 0x3F803F80u;
        *(uint4*)(VTb + 3 * 4112 + k0 * 2) = ones;
    }

    // per-head weights (wave-uniform h -> scalar loads)
    const float* wqp = Wq + h * 9;
    const float* wkp = Wk + h * 9;
    const float* wvp = Wv + h * 9;
    float wq_[9], wk_[9], wv_[9];
#pragma unroll
    for (int i = 0; i < 9; ++i) { wq_[i] = wqp[i]; wk_[i] = wkp[i]; wv_[i] = wvp[i]; }

    __syncthreads();

    const int lane = tid & 63;
    const int wid  = tid >> 6;
    const int qt   = wid & 1;     // q-subtile (32 q)
    const int ks   = wid >> 1;    // k-split (1024 k each)
    const int ql   = lane & 31;
    const int q    = qb * 64 + qt * 32 + ql;

    // u = (x_q Wq) Wk^T * scale * log2(e), from bf16-rounded x (consistent with A)
    const u64 xw = XF[q];
    const float xq0 = bf2f((u32)xw & 0xFFFFu);
    const float xq1 = bf2f(((u32)xw >> 16) & 0xFFFFu);
    const float xq2 = bf2f((u32)(xw >> 32) & 0xFFFFu);
    const float Q0 = xq0 * wq_[0] + xq1 * wq_[3] + xq2 * wq_[6];
    const float Q1 = xq0 * wq_[1] + xq1 * wq_[4] + xq2 * wq_[7];
    const float Q2 = xq0 * wq_[2] + xq1 * wq_[5] + xq2 * wq_[8];
    const float cc = 0.5773502691896258f * 1.4426950408889634f;
    const float u0 = (Q0 * wk_[0] + Q1 * wk_[1] + Q2 * wk_[2]) * cc;
    const float u1 = (Q0 * wk_[3] + Q1 * wk_[4] + Q2 * wk_[5]) * cc;
    const float u2 = (Q0 * wk_[6] + Q1 * wk_[7] + Q2 * wk_[8]) * cc;

    // scores-mfma B operand: B[k, col=q]; lanes>=32 (k=8..15) zero
    UBv Bs;
    Bs.u[0] = (lane < 32) ? pkb(u0, u1) : 0u;
    Bs.u[1] = (lane < 32) ? pkb(u2, 0.f) : 0u;
    Bs.u[2] = 0u; Bs.u[3] = 0u;

    const int xfi = ks * 1024 + ql;
    const char* vtb = VTb + (lane & 3) * 4112 + (ks * 1024 + ((lane >> 5) << 3)) * 2;

    f32x16_t pvC = {};  // C[row=q', col=d(0..3 valid)]
    f32x16_t zc  = {};

    const bool lohalf = (lane < 32);

    // ---- main loop: 32 k-tiles of 32 keys ----
#pragma unroll 4
    for (int t = 0; t < 32; ++t) {
        const u64 aw = XF[xfi + t * 32];
        UBv A; A.u[0] = (u32)aw; A.u[1] = (u32)(aw >> 32); A.u[2] = 0u; A.u[3] = 0u;
        const f32x16_t sc = __builtin_amdgcn_mfma_f32_32x32x16_bf16(A.v, Bs.v, zc, 0, 0, 0);

        float p[16];
#pragma unroll
        for (int i = 0; i < 16; ++i) {
            const float s = fminf(fmaxf(sc[i], -80.f), 80.f);
            p[i] = exp2f(s);
        }

        const uint4 bv0 = *(const uint4*)(vtb + t * 64);
        const uint4 bv1 = *(const uint4*)(vtb + t * 64 + 32);

        // P fragment (keys 0..15)
        {
            const u32 pk01 = pkb(p[0], p[1]), pk23 = pkb(p[2], p[3]);
            const u32 pk45 = pkb(p[4], p[5]), pk67 = pkb(p[6], p[7]);
            const u32 s01 = half_swap(pk01), s23 = half_swap(pk23);
            const u32 s45 = half_swap(pk45), s67 = half_swap(pk67);
            UBv PA;
            PA.u[0] = lohalf ? pk01 : s45;
            PA.u[1] = lohalf ? pk23 : s67;
            PA.u[2] = lohalf ? s01  : pk45;
            PA.u[3] = lohalf ? s23  : pk67;
            UBv B0; B0.u[0] = bv0.x; B0.u[1] = bv0.y; B0.u[2] = bv0.z; B0.u[3] = bv0.w;
            pvC = __builtin_amdgcn_mfma_f32_32x32x16_bf16(PA.v, B0.v, pvC, 0, 0, 0);
        }
        // P fragment (keys 16..31)
        {
            const u32 pk01 = pkb(p[8], p[9]),   pk23 = pkb(p[10], p[11]);
            const u32 pk45 = pkb(p[12], p[13]), pk67 = pkb(p[14], p[15]);
            const u32 s01 = half_swap(pk01), s23 = half_swap(pk23);
            const u32 s45 = half_swap(pk45), s67 = half_swap(pk67);
            UBv PB;
            PB.u[0] = lohalf ? pk01 : s45;
            PB.u[1] = lohalf ? pk23 : s67;
            PB.u[2] = lohalf ? s01  : pk45;
            PB.u[3] = lohalf ? s23  : pk67;
            UBv B1; B1.u[0] = bv1.x; B1.u[1] = bv1.y; B1.u[2] = bv1.z; B1.u[3] = bv1.w;
            pvC = __builtin_amdgcn_mfma_f32_32x32x16_bf16(PB.v, B1.v, pvC, 0, 0, 0);
        }
    }

    // ---- merge k-splits + epilogue ----
    const int d31 = lane & 31;
    if (d31 < 4) {
        const int slot = ((lane >> 5) << 2) | d31;
#pragma unroll
        for (int i = 0; i < 4; ++i) {
            float4 w; w.x = pvC[i * 4 + 0]; w.y = pvC[i * 4 + 1];
            w.z = pvC[i * 4 + 2]; w.w = pvC[i * 4 + 3];
            *(float4*)&RED[wid][slot][i * 4] = w;
        }
    }
    __syncthreads();

    if (wid < 2 && lane < 32) {
        const int qrow = lane;
        const int hh2 = (qrow >> 2) & 1;
        const int r   = (qrow & 3) | ((qrow >> 3) << 2);
        float acc[4];
#pragma unroll
        for (int d = 0; d < 4; ++d)
            acc[d] = RED[wid][hh2 * 4 + d][r] + RED[wid + 2][hh2 * 4 + d][r];
        const float inv = 1.0f / fmaxf(acc[3], 1e-37f);
        const float r0 = acc[0] * inv, r1 = acc[1] * inv, r2 = acc[2] * inv;
        const float o0 = r0 * wv_[0] + r1 * wv_[3] + r2 * wv_[6];
        const float o1 = r0 * wv_[1] + r1 * wv_[4] + r2 * wv_[7];
        const float o2 = r0 * wv_[2] + r1 * wv_[5] + r2 * wv_[8];
        const int qg = qb * 64 + wid * 32 + qrow;
        const int o  = bh * (SEQ * 3) + qg * 3;
        const int second = NB * NH * SEQ * 3;
        out[o + 0] = o0; out[o + 1] = o1; out[o + 2] = o2;
        out[o + second + 0] = o0; out[o + second + 1] = o1; out[o + second + 2] = o2;
    }
}

extern "C" void kernel_launch(void* const* d_in, const int* in_sizes, int n_in,
                              void* d_out, int out_size, void* d_ws, size_t ws_size,
                              hipStream_t stream) {
    const float* x  = (const float*)d_in[0];
    const float* Wq = (const float*)d_in[1];
    const float* Wk = (const float*)d_in[2];
    const float* Wv = (const float*)d_in[3];
    float* out = (float*)d_out;
    (void)in_sizes; (void)n_in; (void)d_ws; (void)ws_size; (void)out_size;

    const int grid = NB * NH * (SEQ / 64);  // 1024 blocks
    attn_mfma<<<grid, 256, 0, stream>>>(x, Wq, Wk, Wv, out);
}

// Round 7
// 30.317 us; speedup vs baseline: 1.8809x; 1.8809x over previous
//
#include <hip/hip_runtime.h>

#define SEQ 2048
#define NH 8
#define NB 4

typedef unsigned int u32;
typedef unsigned long long u64;
typedef short bf16x8_t __attribute__((ext_vector_type(8)));
typedef float f32x16_t __attribute__((ext_vector_type(16)));

// 2^x, raw v_exp_f32 (proven in R1/R2)
__device__ __forceinline__ float exp2_fast(float x) {
    float r; asm("v_exp_f32 %0, %1" : "=v"(r) : "v"(x)); return r;
}
// pack 2 f32 -> 2 bf16, round-half-up: 2x v_add + 1x v_perm_b32 (no asm)
__device__ __forceinline__ u32 pkb(float a, float b) {
    const u32 ua = __builtin_bit_cast(u32, a) + 0x8000u;
    const u32 ub = __builtin_bit_cast(u32, b) + 0x8000u;
    return __builtin_amdgcn_perm(ub, ua, 0x07060302u);  // {ub.hi16, ua.hi16}
}
__device__ __forceinline__ float bf2f(u32 h) {
    return __builtin_bit_cast(float, h << 16);
}
// exchange with lane^32
__device__ __forceinline__ u32 half_swap(u32 v) {
    return (u32)__shfl_xor((int)v, 32, 64);
}

union UBv { bf16x8_t v; u32 u[4]; };

__global__ __launch_bounds__(256)
void attn_mfma(const float* __restrict__ x, const float* __restrict__ Wq,
               const float* __restrict__ Wk, const float* __restrict__ Wv,
               float* __restrict__ out) {
    // XF: per-key packed bf16 {x0,x1},{x2,0} -> scores-mfma A frags (16 KB)
    // VTb: bf16 V'^T rows d=0..3 (x0,x1,x2,ones), row stride 4112 B
    // RED: cross-wave partials
    __shared__ u64 XF[SEQ];
    __shared__ __align__(16) char VTb[4 * 4112];
    __shared__ __align__(16) float RED[4][8][16];

    const int tid = threadIdx.x;
    const int blk = blockIdx.x;
    const int qb  = blk & 31;      // 64-query tile
    const int bh  = blk >> 5;
    const int h   = bh & 7;
    const int b   = bh >> 3;

    // ---- staging: 8 keys per thread ----
    {
        const float4* xg = (const float4*)(x + b * SEQ * 3);
        float xv[24];
        const float4 t0 = xg[tid * 6 + 0]; xv[0]=t0.x; xv[1]=t0.y; xv[2]=t0.z; xv[3]=t0.w;
        const float4 t1 = xg[tid * 6 + 1]; xv[4]=t1.x; xv[5]=t1.y; xv[6]=t1.z; xv[7]=t1.w;
        const float4 t2 = xg[tid * 6 + 2]; xv[8]=t2.x; xv[9]=t2.y; xv[10]=t2.z; xv[11]=t2.w;
        const float4 t3 = xg[tid * 6 + 3]; xv[12]=t3.x; xv[13]=t3.y; xv[14]=t3.z; xv[15]=t3.w;
        const float4 t4 = xg[tid * 6 + 4]; xv[16]=t4.x; xv[17]=t4.y; xv[18]=t4.z; xv[19]=t4.w;
        const float4 t5 = xg[tid * 6 + 5]; xv[20]=t5.x; xv[21]=t5.y; xv[22]=t5.z; xv[23]=t5.w;
        const int k0 = tid * 8;
#pragma unroll
        for (int j = 0; j < 8; j += 2) {
            uint4 w;
            w.x = pkb(xv[3*j + 0], xv[3*j + 1]);
            w.y = pkb(xv[3*j + 2], 0.f);
            w.z = pkb(xv[3*j + 3], xv[3*j + 4]);
            w.w = pkb(xv[3*j + 5], 0.f);
            *(uint4*)&XF[k0 + j] = w;
        }
#pragma unroll
        for (int d = 0; d < 3; ++d) {
            uint4 w;
            w.x = pkb(xv[0 + d],  xv[3 + d]);
            w.y = pkb(xv[6 + d],  xv[9 + d]);
            w.z = pkb(xv[12 + d], xv[15 + d]);
            w.w = pkb(xv[18 + d], xv[21 + d]);
            *(uint4*)(VTb + d * 4112 + k0 * 2) = w;
        }
        uint4 ones; ones.x = ones.y = ones.z = ones.w = 0x3F803F80u;
        *(uint4*)(VTb + 3 * 4112 + k0 * 2) = ones;
    }

    // per-head weights (wave-uniform h -> scalar loads)
    const float* wqp = Wq + h * 9;
    const float* wkp = Wk + h * 9;
    const float* wvp = Wv + h * 9;
    float wq_[9], wk_[9], wv_[9];
#pragma unroll
    for (int i = 0; i < 9; ++i) { wq_[i] = wqp[i]; wk_[i] = wkp[i]; wv_[i] = wvp[i]; }

    __syncthreads();

    const int lane = tid & 63;
    const int wid  = tid >> 6;
    const int qt   = wid & 1;     // q-subtile (32 q)
    const int ks   = wid >> 1;    // k-split (1024 k each)
    const int ql   = lane & 31;
    const int q    = qb * 64 + qt * 32 + ql;

    // u = (x_q Wq) Wk^T * scale * log2(e), from bf16-rounded x (consistent with A)
    const u64 xw = XF[q];
    const float xq0 = bf2f((u32)xw & 0xFFFFu);
    const float xq1 = bf2f(((u32)xw >> 16) & 0xFFFFu);
    const float xq2 = bf2f((u32)(xw >> 32) & 0xFFFFu);
    const float Q0 = xq0 * wq_[0] + xq1 * wq_[3] + xq2 * wq_[6];
    const float Q1 = xq0 * wq_[1] + xq1 * wq_[4] + xq2 * wq_[7];
    const float Q2 = xq0 * wq_[2] + xq1 * wq_[5] + xq2 * wq_[8];
    const float cc = 0.5773502691896258f * 1.4426950408889634f;
    const float u0 = (Q0 * wk_[0] + Q1 * wk_[1] + Q2 * wk_[2]) * cc;
    const float u1 = (Q0 * wk_[3] + Q1 * wk_[4] + Q2 * wk_[5]) * cc;
    const float u2 = (Q0 * wk_[6] + Q1 * wk_[7] + Q2 * wk_[8]) * cc;

    // scores-mfma B operand: B[k, col=q]; lanes>=32 (k=8..15) zero
    UBv Bs;
    Bs.u[0] = (lane < 32) ? pkb(u0, u1) : 0u;
    Bs.u[1] = (lane < 32) ? pkb(u2, 0.f) : 0u;
    Bs.u[2] = 0u; Bs.u[3] = 0u;

    const int xfi = ks * 1024 + ql;
    const char* vtb = VTb + (lane & 3) * 4112 + (ks * 1024 + ((lane >> 5) << 3)) * 2;

    f32x16_t pvC = {};  // C[row=q', col=d(0..3 valid)]
    f32x16_t zc  = {};

    const bool lohalf = (lane < 32);

    // ---- main loop: 32 k-tiles of 32 keys ----
#pragma unroll 4
    for (int t = 0; t < 32; ++t) {
        const u64 aw = XF[xfi + t * 32];
        UBv A; A.u[0] = (u32)aw; A.u[1] = (u32)(aw >> 32); A.u[2] = 0u; A.u[3] = 0u;
        const f32x16_t sc = __builtin_amdgcn_mfma_f32_32x32x16_bf16(A.v, Bs.v, zc, 0, 0, 0);

        float p[16];
#pragma unroll
        for (int i = 0; i < 16; ++i) p[i] = exp2_fast(sc[i]);

        const uint4 bv0 = *(const uint4*)(vtb + t * 64);
        const uint4 bv1 = *(const uint4*)(vtb + t * 64 + 32);

        // P fragment (keys 0..15)
        {
            const u32 pk01 = pkb(p[0], p[1]), pk23 = pkb(p[2], p[3]);
            const u32 pk45 = pkb(p[4], p[5]), pk67 = pkb(p[6], p[7]);
            const u32 s01 = half_swap(pk01), s23 = half_swap(pk23);
            const u32 s45 = half_swap(pk45), s67 = half_swap(pk67);
            UBv PA;
            PA.u[0] = lohalf ? pk01 : s45;
            PA.u[1] = lohalf ? pk23 : s67;
            PA.u[2] = lohalf ? s01  : pk45;
            PA.u[3] = lohalf ? s23  : pk67;
            UBv B0; B0.u[0] = bv0.x; B0.u[1] = bv0.y; B0.u[2] = bv0.z; B0.u[3] = bv0.w;
            pvC = __builtin_amdgcn_mfma_f32_32x32x16_bf16(PA.v, B0.v, pvC, 0, 0, 0);
        }
        // P fragment (keys 16..31)
        {
            const u32 pk01 = pkb(p[8], p[9]),   pk23 = pkb(p[10], p[11]);
            const u32 pk45 = pkb(p[12], p[13]), pk67 = pkb(p[14], p[15]);
            const u32 s01 = half_swap(pk01), s23 = half_swap(pk23);
            const u32 s45 = half_swap(pk45), s67 = half_swap(pk67);
            UBv PB;
            PB.u[0] = lohalf ? pk01 : s45;
            PB.u[1] = lohalf ? pk23 : s67;
            PB.u[2] = lohalf ? s01  : pk45;
            PB.u[3] = lohalf ? s23  : pk67;
            UBv B1; B1.u[0] = bv1.x; B1.u[1] = bv1.y; B1.u[2] = bv1.z; B1.u[3] = bv1.w;
            pvC = __builtin_amdgcn_mfma_f32_32x32x16_bf16(PB.v, B1.v, pvC, 0, 0, 0);
        }
    }

    // ---- merge k-splits + epilogue ----
    const int d31 = lane & 31;
    if (d31 < 4) {
        const int slot = ((lane >> 5) << 2) | d31;
#pragma unroll
        for (int i = 0; i < 4; ++i) {
            float4 w; w.x = pvC[i * 4 + 0]; w.y = pvC[i * 4 + 1];
            w.z = pvC[i * 4 + 2]; w.w = pvC[i * 4 + 3];
            *(float4*)&RED[wid][slot][i * 4] = w;
        }
    }
    __syncthreads();

    if (wid < 2 && lane < 32) {
        const int qrow = lane;
        const int hh2 = (qrow >> 2) & 1;
        const int r   = (qrow & 3) | ((qrow >> 3) << 2);
        float acc[4];
#pragma unroll
        for (int d = 0; d < 4; ++d)
            acc[d] = RED[wid][hh2 * 4 + d][r] + RED[wid + 2][hh2 * 4 + d][r];
        const float inv = 1.0f / fmaxf(acc[3], 1e-37f);
        const float r0 = acc[0] * inv, r1 = acc[1] * inv, r2 = acc[2] * inv;
        const float o0 = r0 * wv_[0] + r1 * wv_[3] + r2 * wv_[6];
        const float o1 = r0 * wv_[1] + r1 * wv_[4] + r2 * wv_[7];
        const float o2 = r0 * wv_[2] + r1 * wv_[5] + r2 * wv_[8];
        const int qg = qb * 64 + wid * 32 + qrow;
        const int o  = bh * (SEQ * 3) + qg * 3;
        const int second = NB * NH * SEQ * 3;
        out[o + 0] = o0; out[o + 1] = o1; out[o + 2] = o2;
        out[o + second + 0] = o0; out[o + second + 1] = o1; out[o + second + 2] = o2;
    }
}

extern "C" void kernel_launch(void* const* d_in, const int* in_sizes, int n_in,
                              void* d_out, int out_size, void* d_ws, size_t ws_size,
                              hipStream_t stream) {
    const float* x  = (const float*)d_in[0];
    const float* Wq = (const float*)d_in[1];
    const float* Wk = (const float*)d_in[2];
    const float* Wv = (const float*)d_in[3];
    float* out = (float*)d_out;
    (void)in_sizes; (void)n_in; (void)d_ws; (void)ws_size; (void)out_size;

    const int grid = NB * NH * (SEQ / 64);  // 1024 blocks
    attn_mfma<<<grid, 256, 0, stream>>>(x, Wq, Wk, Wv, out);
}

// Round 8
// 27.864 us; speedup vs baseline: 2.0465x; 1.0880x over previous
//
#include <hip/hip_runtime.h>

#define SEQ 2048
#define NH 8
#define NB 4

typedef unsigned int u32;
typedef unsigned long long u64;
typedef short bf16x8_t __attribute__((ext_vector_type(8)));
typedef float f32x16_t __attribute__((ext_vector_type(16)));

// 2^x, raw v_exp_f32 (proven R1/R2/R7)
__device__ __forceinline__ float exp2_fast(float x) {
    float r; asm("v_exp_f32 %0, %1" : "=v"(r) : "v"(x)); return r;
}
// pack 2 f32 -> 2 bf16, round-half-up: 2x v_add + 1x v_perm_b32 (proven R7)
__device__ __forceinline__ u32 pkb(float a, float b) {
    const u32 ua = __builtin_bit_cast(u32, a) + 0x8000u;
    const u32 ub = __builtin_bit_cast(u32, b) + 0x8000u;
    return __builtin_amdgcn_perm(ub, ua, 0x07060302u);  // {ub.hi16, ua.hi16}
}
__device__ __forceinline__ float bf2f(u32 h) {
    return __builtin_bit_cast(float, h << 16);
}

union UBv { bf16x8_t v; u32 u[4]; };

__global__ __launch_bounds__(256)
void attn_mfma(const float* __restrict__ x, const float* __restrict__ Wq,
               const float* __restrict__ Wk, const float* __restrict__ Wv,
               float* __restrict__ out) {
    // XF: per-key packed bf16 {x0,x1},{x2,0} -> scores-mfma A frags (natural key order)
    // VTb: bf16 V'^T rows d=0..3 (x0,x1,x2,ones), row stride 4112 B.
    //      KEY ORDER PERMUTED: key m stored at slot (m with bits2<->3 swapped), so the
    //      scores-C register order == PV-A slot order (no cross-lane swap needed).
    // RED: cross-wave partials
    __shared__ u64 XF[SEQ];
    __shared__ __align__(16) char VTb[4 * 4112];
    __shared__ __align__(16) float RED[4][8][16];

    const int tid = threadIdx.x;
    const int blk = blockIdx.x;
    const int qb  = blk & 31;      // 64-query tile
    const int bh  = blk >> 5;
    const int h   = bh & 7;
    const int b   = bh >> 3;

    // ---- staging: 8 keys per thread ----
    {
        const float4* xg = (const float4*)(x + b * SEQ * 3);
        float xv[24];
        const float4 t0 = xg[tid * 6 + 0]; xv[0]=t0.x; xv[1]=t0.y; xv[2]=t0.z; xv[3]=t0.w;
        const float4 t1 = xg[tid * 6 + 1]; xv[4]=t1.x; xv[5]=t1.y; xv[6]=t1.z; xv[7]=t1.w;
        const float4 t2 = xg[tid * 6 + 2]; xv[8]=t2.x; xv[9]=t2.y; xv[10]=t2.z; xv[11]=t2.w;
        const float4 t3 = xg[tid * 6 + 3]; xv[12]=t3.x; xv[13]=t3.y; xv[14]=t3.z; xv[15]=t3.w;
        const float4 t4 = xg[tid * 6 + 4]; xv[16]=t4.x; xv[17]=t4.y; xv[18]=t4.z; xv[19]=t4.w;
        const float4 t5 = xg[tid * 6 + 5]; xv[20]=t5.x; xv[21]=t5.y; xv[22]=t5.z; xv[23]=t5.w;
        const int k0 = tid * 8;
#pragma unroll
        for (int j = 0; j < 8; j += 2) {
            uint4 w;
            w.x = pkb(xv[3*j + 0], xv[3*j + 1]);
            w.y = pkb(xv[3*j + 2], 0.f);
            w.z = pkb(xv[3*j + 3], xv[3*j + 4]);
            w.w = pkb(xv[3*j + 5], 0.f);
            *(uint4*)&XF[k0 + j] = w;
        }
        // permuted V^T staging: this thread's 8 keys (aligned group) split into
        // two 4-key runs at slots slotA (keys k0..k0+3) and slotA+8 (keys k0+4..k0+7)
        const int slotA = (k0 & ~15) + ((k0 >> 3) & 1) * 4;
#pragma unroll
        for (int d = 0; d < 3; ++d) {
            uint2 wa, wb;
            wa.x = pkb(xv[0 + d],  xv[3 + d]);
            wa.y = pkb(xv[6 + d],  xv[9 + d]);
            wb.x = pkb(xv[12 + d], xv[15 + d]);
            wb.y = pkb(xv[18 + d], xv[21 + d]);
            *(uint2*)(VTb + d * 4112 + slotA * 2)       = wa;
            *(uint2*)(VTb + d * 4112 + (slotA + 8) * 2) = wb;
        }
        uint4 ones; ones.x = ones.y = ones.z = ones.w = 0x3F803F80u;
        *(uint4*)(VTb + 3 * 4112 + k0 * 2) = ones;   // uniform row: order irrelevant
    }

    // per-head weights (wave-uniform h -> scalar loads)
    const float* wqp = Wq + h * 9;
    const float* wkp = Wk + h * 9;
    const float* wvp = Wv + h * 9;
    float wq_[9], wk_[9], wv_[9];
#pragma unroll
    for (int i = 0; i < 9; ++i) { wq_[i] = wqp[i]; wk_[i] = wkp[i]; wv_[i] = wvp[i]; }

    __syncthreads();

    const int lane = tid & 63;
    const int wid  = tid >> 6;
    const int qt   = wid & 1;     // q-subtile (32 q)
    const int ks   = wid >> 1;    // k-split (1024 k each)
    const int ql   = lane & 31;
    const int q    = qb * 64 + qt * 32 + ql;

    // u = (x_q Wq) Wk^T * scale * log2(e), from bf16-rounded x (consistent with A)
    const u64 xw = XF[q];
    const float xq0 = bf2f((u32)xw & 0xFFFFu);
    const float xq1 = bf2f(((u32)xw >> 16) & 0xFFFFu);
    const float xq2 = bf2f((u32)(xw >> 32) & 0xFFFFu);
    const float Q0 = xq0 * wq_[0] + xq1 * wq_[3] + xq2 * wq_[6];
    const float Q1 = xq0 * wq_[1] + xq1 * wq_[4] + xq2 * wq_[7];
    const float Q2 = xq0 * wq_[2] + xq1 * wq_[5] + xq2 * wq_[8];
    const float cc = 0.5773502691896258f * 1.4426950408889634f;
    const float u0 = (Q0 * wk_[0] + Q1 * wk_[1] + Q2 * wk_[2]) * cc;
    const float u1 = (Q0 * wk_[3] + Q1 * wk_[4] + Q2 * wk_[5]) * cc;
    const float u2 = (Q0 * wk_[6] + Q1 * wk_[7] + Q2 * wk_[8]) * cc;

    // scores-mfma B operand: B[k, col=q]; lanes>=32 (k=8..15) zero
    UBv Bs;
    Bs.u[0] = (lane < 32) ? pkb(u0, u1) : 0u;
    Bs.u[1] = (lane < 32) ? pkb(u2, 0.f) : 0u;
    Bs.u[2] = 0u; Bs.u[3] = 0u;

    const int xfi = ks * 1024 + ql;
    const char* vtb = VTb + (lane & 3) * 4112 + (ks * 1024 + ((lane >> 5) << 3)) * 2;

    f32x16_t pvC = {};  // C[row=q', col=d(0..3 valid)]
    f32x16_t zc  = {};

    // ---- main loop: 32 k-tiles of 32 keys; no cross-lane ops ----
#pragma unroll 4
    for (int t = 0; t < 32; ++t) {
        const u64 aw = XF[xfi + t * 32];
        UBv A; A.u[0] = (u32)aw; A.u[1] = (u32)(aw >> 32); A.u[2] = 0u; A.u[3] = 0u;
        const f32x16_t sc = __builtin_amdgcn_mfma_f32_32x32x16_bf16(A.v, Bs.v, zc, 0, 0, 0);

        float p[16];
#pragma unroll
        for (int i = 0; i < 16; ++i) p[i] = exp2_fast(sc[i]);

        const uint4 bv0 = *(const uint4*)(vtb + t * 64);
        const uint4 bv1 = *(const uint4*)(vtb + t * 64 + 32);

        // P fragments: own registers pairwise = PV-A layout (V key-order pre-permuted)
        UBv PA;
        PA.u[0] = pkb(p[0], p[1]); PA.u[1] = pkb(p[2], p[3]);
        PA.u[2] = pkb(p[4], p[5]); PA.u[3] = pkb(p[6], p[7]);
        UBv B0; B0.u[0] = bv0.x; B0.u[1] = bv0.y; B0.u[2] = bv0.z; B0.u[3] = bv0.w;
        pvC = __builtin_amdgcn_mfma_f32_32x32x16_bf16(PA.v, B0.v, pvC, 0, 0, 0);

        UBv PB;
        PB.u[0] = pkb(p[8],  p[9]);  PB.u[1] = pkb(p[10], p[11]);
        PB.u[2] = pkb(p[12], p[13]); PB.u[3] = pkb(p[14], p[15]);
        UBv B1; B1.u[0] = bv1.x; B1.u[1] = bv1.y; B1.u[2] = bv1.z; B1.u[3] = bv1.w;
        pvC = __builtin_amdgcn_mfma_f32_32x32x16_bf16(PB.v, B1.v, pvC, 0, 0, 0);
    }

    // ---- merge k-splits + epilogue ----
    const int d31 = lane & 31;
    if (d31 < 4) {
        const int slot = ((lane >> 5) << 2) | d31;
#pragma unroll
        for (int i = 0; i < 4; ++i) {
            float4 w; w.x = pvC[i * 4 + 0]; w.y = pvC[i * 4 + 1];
            w.z = pvC[i * 4 + 2]; w.w = pvC[i * 4 + 3];
            *(float4*)&RED[wid][slot][i * 4] = w;
        }
    }
    __syncthreads();

    if (wid < 2 && lane < 32) {
        const int qrow = lane;
        const int hh2 = (qrow >> 2) & 1;
        const int r   = (qrow & 3) | ((qrow >> 3) << 2);
        float acc[4];
#pragma unroll
        for (int d = 0; d < 4; ++d)
            acc[d] = RED[wid][hh2 * 4 + d][r] + RED[wid + 2][hh2 * 4 + d][r];
        const float inv = 1.0f / fmaxf(acc[3], 1e-37f);
        const float r0 = acc[0] * inv, r1 = acc[1] * inv, r2 = acc[2] * inv;
        const float o0 = r0 * wv_[0] + r1 * wv_[3] + r2 * wv_[6];
        const float o1 = r0 * wv_[1] + r1 * wv_[4] + r2 * wv_[7];
        const float o2 = r0 * wv_[2] + r1 * wv_[5] + r2 * wv_[8];
        const int qg = qb * 64 + wid * 32 + qrow;
        const int o  = bh * (SEQ * 3) + qg * 3;
        const int second = NB * NH * SEQ * 3;
        out[o + 0] = o0; out[o + 1] = o1; out[o + 2] = o2;
        out[o + second + 0] = o0; out[o + second + 1] = o1; out[o + second + 2] = o2;
    }
}

extern "C" void kernel_launch(void* const* d_in, const int* in_sizes, int n_in,
                              void* d_out, int out_size, void* d_ws, size_t ws_size,
                              hipStream_t stream) {
    const float* x  = (const float*)d_in[0];
    const float* Wq = (const float*)d_in[1];
    const float* Wk = (const float*)d_in[2];
    const float* Wv = (const float*)d_in[3];
    float* out = (float*)d_out;
    (void)in_sizes; (void)n_in; (void)d_ws; (void)ws_size; (void)out_size;

    const int grid = NB * NH * (SEQ / 64);  // 1024 blocks
    attn_mfma<<<grid, 256, 0, stream>>>(x, Wq, Wk, Wv, out);
}

// Round 9
// 26.109 us; speedup vs baseline: 2.1841x; 1.0672x over previous
//
#include <hip/hip_runtime.h>

#define SEQ 2048
#define NH 8
#define NB 4

typedef unsigned int u32;
typedef unsigned long long u64;
typedef short bf16x8_t __attribute__((ext_vector_type(8)));
typedef float f32x16_t __attribute__((ext_vector_type(16)));

// 2^x, raw v_exp_f32 (proven R1/R2/R7/R8)
__device__ __forceinline__ float exp2_fast(float x) {
    float r; asm("v_exp_f32 %0, %1" : "=v"(r) : "v"(x)); return r;
}
// pack 2 f32 -> 2 bf16, round-half-up: 2x v_add + 1x v_perm_b32 (proven R7/R8)
__device__ __forceinline__ u32 pkb(float a, float b) {
    const u32 ua = __builtin_bit_cast(u32, a) + 0x8000u;
    const u32 ub = __builtin_bit_cast(u32, b) + 0x8000u;
    return __builtin_amdgcn_perm(ub, ua, 0x07060302u);  // {ub.hi16, ua.hi16}
}

union UBv { bf16x8_t v; u32 u[4]; };

__global__ __launch_bounds__(256)
void attn_mfma(const float* __restrict__ x, const float* __restrict__ Wq,
               const float* __restrict__ Wk, const float* __restrict__ Wv,
               float* __restrict__ out) {
    // VT4: [kt=128][d=4][c=16] bf16 tiles, rows d = {x0,x1,x2,ones}  (16 KB)
    //      serves PV-B (pi-mapped b64 reads) and x2 of scores-A (u16 read)
    // XQ : per-key packed bf16 {x0,x1} -> scores-A word0               (8 KB)
    // RED: cross-wave partials                                          (2 KB)
    __shared__ __align__(16) char VT4[128 * 128];
    __shared__ u32 XQ[SEQ];
    __shared__ __align__(16) float RED[4][8][16];

    const int tid = threadIdx.x;
    const int blk = blockIdx.x;
    const int qb  = blk & 63;      // 32-query tile (64 per bh)
    const int bh  = blk >> 6;
    const int h   = bh & 7;
    const int b   = bh >> 3;

    // ---- staging: 8 keys per thread ----
    {
        const float4* xg = (const float4*)(x + b * SEQ * 3);
        float xv[24];
        const float4 t0 = xg[tid * 6 + 0]; xv[0]=t0.x; xv[1]=t0.y; xv[2]=t0.z; xv[3]=t0.w;
        const float4 t1 = xg[tid * 6 + 1]; xv[4]=t1.x; xv[5]=t1.y; xv[6]=t1.z; xv[7]=t1.w;
        const float4 t2 = xg[tid * 6 + 2]; xv[8]=t2.x; xv[9]=t2.y; xv[10]=t2.z; xv[11]=t2.w;
        const float4 t3 = xg[tid * 6 + 3]; xv[12]=t3.x; xv[13]=t3.y; xv[14]=t3.z; xv[15]=t3.w;
        const float4 t4 = xg[tid * 6 + 4]; xv[16]=t4.x; xv[17]=t4.y; xv[18]=t4.z; xv[19]=t4.w;
        const float4 t5 = xg[tid * 6 + 5]; xv[20]=t5.x; xv[21]=t5.y; xv[22]=t5.z; xv[23]=t5.w;
        const int k0 = tid * 8;
        const int kt = tid >> 1;          // 16-key tile index
        const int c0 = (tid & 1) * 8;     // col offset within tile
        // XQ: {x0,x1} per key
        uint4 w1, w2;
        w1.x = pkb(xv[0],  xv[1]);  w1.y = pkb(xv[3],  xv[4]);
        w1.z = pkb(xv[6],  xv[7]);  w1.w = pkb(xv[9],  xv[10]);
        w2.x = pkb(xv[12], xv[13]); w2.y = pkb(xv[15], xv[16]);
        w2.z = pkb(xv[18], xv[19]); w2.w = pkb(xv[21], xv[22]);
        *(uint4*)&XQ[k0]     = w1;
        *(uint4*)&XQ[k0 + 4] = w2;
        // VT4 rows d=0..2 (natural key order), d=3 ones
#pragma unroll
        for (int d = 0; d < 3; ++d) {
            uint4 w;
            w.x = pkb(xv[0 + d],  xv[3 + d]);
            w.y = pkb(xv[6 + d],  xv[9 + d]);
            w.z = pkb(xv[12 + d], xv[15 + d]);
            w.w = pkb(xv[18 + d], xv[21 + d]);
            *(uint4*)(VT4 + kt * 128 + d * 32 + c0 * 2) = w;
        }
        uint4 ones; ones.x = ones.y = ones.z = ones.w = 0x3F803F80u;
        *(uint4*)(VT4 + kt * 128 + 3 * 32 + c0 * 2) = ones;
    }

    // per-head weights (wave-uniform h -> scalar loads)
    const float* wqp = Wq + h * 9;
    const float* wkp = Wk + h * 9;
    const float* wvp = Wv + h * 9;
    float wq_[9], wk_[9], wv_[9];
#pragma unroll
    for (int i = 0; i < 9; ++i) { wq_[i] = wqp[i]; wk_[i] = wkp[i]; wv_[i] = wvp[i]; }

    const int lane = tid & 63;
    const int wid  = tid >> 6;    // k-split: 512 keys per wave
    const int ql   = lane & 31;
    const int q    = qb * 32 + ql;

    // u = (x_q Wq) Wk^T * scale * log2(e) from f32 x (global, L2-hot)
    const float* gq = x + b * SEQ * 3 + q * 3;
    const float xq0 = gq[0], xq1 = gq[1], xq2 = gq[2];
    const float Q0 = xq0 * wq_[0] + xq1 * wq_[3] + xq2 * wq_[6];
    const float Q1 = xq0 * wq_[1] + xq1 * wq_[4] + xq2 * wq_[7];
    const float Q2 = xq0 * wq_[2] + xq1 * wq_[5] + xq2 * wq_[8];
    const float cc = 0.5773502691896258f * 1.4426950408889634f;
    const float u0 = (Q0 * wk_[0] + Q1 * wk_[1] + Q2 * wk_[2]) * cc;
    const float u1 = (Q0 * wk_[3] + Q1 * wk_[4] + Q2 * wk_[5]) * cc;
    const float u2 = (Q0 * wk_[6] + Q1 * wk_[7] + Q2 * wk_[8]) * cc;

    __syncthreads();

    // scores-mfma B operand: B[k, col=q]; lanes>=32 (k=8..15) zero
    UBv Bs;
    Bs.u[0] = (lane < 32) ? pkb(u0, u1) : 0u;
    Bs.u[1] = (lane < 32) ? pkb(u2, 0.f) : 0u;
    Bs.u[2] = 0u; Bs.u[3] = 0u;

    // per-wave addresses
    const int   kbase = wid * 512;
    const u32*  xqp   = &XQ[kbase + ql];                                     // A word0
    const char* x2a   = VT4 + wid * 4096 + ((lane >> 4) & 1) * 128 + 64 + (lane & 15) * 2;  // A word1 (u16)
    const char* vb    = VT4 + wid * 4096 + (lane & 3) * 32 + (lane >> 5) * 8;               // PV-B base

    f32x16_t pvC = {};  // C[row=q', col: 0..3 = {a0,a1,a2,l} (cols repeat mod 4)]
    f32x16_t zc  = {};

    // ---- main loop: 16 k-tiles of 32 keys per wave ----
#pragma unroll 4
    for (int t = 0; t < 16; ++t) {
        // A frag: {x0,x1} from XQ, {x2,0} via zero-extending u16 from VT4 row 2
        const u32 a0 = xqp[t * 32];
        const u32 a1 = (u32)*(const unsigned short*)(x2a + t * 256);
        // PV-B frags, pi-mapped (pi = bit2<->bit3 swap within 16 keys)
        const uint2 b0a = *(const uint2*)(vb + t * 256 + 0);
        const uint2 b0b = *(const uint2*)(vb + t * 256 + 16);
        const uint2 b1a = *(const uint2*)(vb + t * 256 + 128);
        const uint2 b1b = *(const uint2*)(vb + t * 256 + 144);

        UBv A; A.u[0] = a0; A.u[1] = a1; A.u[2] = 0u; A.u[3] = 0u;
        const f32x16_t sc = __builtin_amdgcn_mfma_f32_32x32x16_bf16(A.v, Bs.v, zc, 0, 0, 0);

        UBv PA;
        PA.u[0] = pkb(exp2_fast(sc[0]), exp2_fast(sc[1]));
        PA.u[1] = pkb(exp2_fast(sc[2]), exp2_fast(sc[3]));
        PA.u[2] = pkb(exp2_fast(sc[4]), exp2_fast(sc[5]));
        PA.u[3] = pkb(exp2_fast(sc[6]), exp2_fast(sc[7]));
        UBv B0; B0.u[0] = b0a.x; B0.u[1] = b0a.y; B0.u[2] = b0b.x; B0.u[3] = b0b.y;
        pvC = __builtin_amdgcn_mfma_f32_32x32x16_bf16(PA.v, B0.v, pvC, 0, 0, 0);

        UBv PB;
        PB.u[0] = pkb(exp2_fast(sc[8]),  exp2_fast(sc[9]));
        PB.u[1] = pkb(exp2_fast(sc[10]), exp2_fast(sc[11]));
        PB.u[2] = pkb(exp2_fast(sc[12]), exp2_fast(sc[13]));
        PB.u[3] = pkb(exp2_fast(sc[14]), exp2_fast(sc[15]));
        UBv B1; B1.u[0] = b1a.x; B1.u[1] = b1a.y; B1.u[2] = b1b.x; B1.u[3] = b1b.y;
        pvC = __builtin_amdgcn_mfma_f32_32x32x16_bf16(PB.v, B1.v, pvC, 0, 0, 0);
    }

    // ---- merge 4 k-splits + epilogue ----
    const int d31 = lane & 31;
    if (d31 < 4) {
        const int slot = ((lane >> 5) << 2) | d31;
#pragma unroll
        for (int i = 0; i < 4; ++i) {
            float4 w; w.x = pvC[i * 4 + 0]; w.y = pvC[i * 4 + 1];
            w.z = pvC[i * 4 + 2]; w.w = pvC[i * 4 + 3];
            *(float4*)&RED[wid][slot][i * 4] = w;
        }
    }
    __syncthreads();

    if (wid == 0 && lane < 32) {
        const int qrow = lane;
        const int hh2 = (qrow >> 2) & 1;
        const int r   = (qrow & 3) | ((qrow >> 3) << 2);
        float acc[4];
#pragma unroll
        for (int d = 0; d < 4; ++d)
            acc[d] = (RED[0][hh2 * 4 + d][r] + RED[1][hh2 * 4 + d][r])
                   + (RED[2][hh2 * 4 + d][r] + RED[3][hh2 * 4 + d][r]);
        const float inv = 1.0f / fmaxf(acc[3], 1e-37f);
        const float r0 = acc[0] * inv, r1 = acc[1] * inv, r2 = acc[2] * inv;
        const float o0 = r0 * wv_[0] + r1 * wv_[3] + r2 * wv_[6];
        const float o1 = r0 * wv_[1] + r1 * wv_[4] + r2 * wv_[7];
        const float o2 = r0 * wv_[2] + r1 * wv_[5] + r2 * wv_[8];
        const int qg = qb * 32 + qrow;
        const int o  = bh * (SEQ * 3) + qg * 3;
        const int second = NB * NH * SEQ * 3;
        out[o + 0] = o0; out[o + 1] = o1; out[o + 2] = o2;
        out[o + second + 0] = o0; out[o + second + 1] = o1; out[o + second + 2] = o2;
    }
}

extern "C" void kernel_launch(void* const* d_in, const int* in_sizes, int n_in,
                              void* d_out, int out_size, void* d_ws, size_t ws_size,
                              hipStream_t stream) {
    const float* x  = (const float*)d_in[0];
    const float* Wq = (const float*)d_in[1];
    const float* Wk = (const float*)d_in[2];
    const float* Wv = (const float*)d_in[3];
    float* out = (float*)d_out;
    (void)in_sizes; (void)n_in; (void)d_ws; (void)ws_size; (void)out_size;

    const int grid = NB * NH * (SEQ / 32);  // 2048 blocks
    attn_mfma<<<grid, 256, 0, stream>>>(x, Wq, Wk, Wv, out);
}

// Round 10
// 25.525 us; speedup vs baseline: 2.2341x; 1.0229x over previous
//
#include <hip/hip_runtime.h>

#define SEQ 2048
#define NH 8
#define NB 4

typedef unsigned int u32;
typedef unsigned long long u64;
typedef short bf16x8_t __attribute__((ext_vector_type(8)));
typedef float f32x16_t __attribute__((ext_vector_type(16)));

// 2^x, raw v_exp_f32 (proven R1/R2/R7/R8/R9)
__device__ __forceinline__ float exp2_fast(float x) {
    float r; asm("v_exp_f32 %0, %1" : "=v"(r) : "v"(x)); return r;
}
// pack 2 f32 -> 2 bf16, round-half-up: 2x v_add + 1x v_perm_b32 (proven R7/R8/R9)
__device__ __forceinline__ u32 pkb(float a, float b) {
    const u32 ua = __builtin_bit_cast(u32, a) + 0x8000u;
    const u32 ub = __builtin_bit_cast(u32, b) + 0x8000u;
    return __builtin_amdgcn_perm(ub, ua, 0x07060302u);  // {ub.hi16, ua.hi16}
}

union UBv { bf16x8_t v; u32 u[4]; };

__global__ __launch_bounds__(256)
void attn_mfma(const float* __restrict__ x, const float* __restrict__ Wq,
               const float* __restrict__ Wk, const float* __restrict__ Wv,
               float* __restrict__ out) {
    // VT4: [kt=128][d=4][c=16] bf16 tiles, rows d = {x0,x1,x2,ones}  (16 KB)
    // XQ : per-key packed bf16 {x0,x1} -> scores-A word0               (8 KB)
    // RED: cross-wave partials                                          (2 KB)
    __shared__ __align__(16) char VT4[128 * 128];
    __shared__ u32 XQ[SEQ];
    __shared__ __align__(16) float RED[4][8][16];

    const int tid = threadIdx.x;
    const int blk = blockIdx.x;
    const int qb  = blk & 63;      // 32-query tile (64 per bh)
    const int bh  = blk >> 6;
    const int h   = bh & 7;
    const int b   = bh >> 3;

    // ---- staging: 8 keys per thread ----
    {
        const float4* xg = (const float4*)(x + b * SEQ * 3);
        float xv[24];
        const float4 t0 = xg[tid * 6 + 0]; xv[0]=t0.x; xv[1]=t0.y; xv[2]=t0.z; xv[3]=t0.w;
        const float4 t1 = xg[tid * 6 + 1]; xv[4]=t1.x; xv[5]=t1.y; xv[6]=t1.z; xv[7]=t1.w;
        const float4 t2 = xg[tid * 6 + 2]; xv[8]=t2.x; xv[9]=t2.y; xv[10]=t2.z; xv[11]=t2.w;
        const float4 t3 = xg[tid * 6 + 3]; xv[12]=t3.x; xv[13]=t3.y; xv[14]=t3.z; xv[15]=t3.w;
        const float4 t4 = xg[tid * 6 + 4]; xv[16]=t4.x; xv[17]=t4.y; xv[18]=t4.z; xv[19]=t4.w;
        const float4 t5 = xg[tid * 6 + 5]; xv[20]=t5.x; xv[21]=t5.y; xv[22]=t5.z; xv[23]=t5.w;
        const int k0 = tid * 8;
        const int kt = tid >> 1;          // 16-key tile index
        const int c0 = (tid & 1) * 8;     // col offset within tile
        // XQ: {x0,x1} per key
        uint4 w1, w2;
        w1.x = pkb(xv[0],  xv[1]);  w1.y = pkb(xv[3],  xv[4]);
        w1.z = pkb(xv[6],  xv[7]);  w1.w = pkb(xv[9],  xv[10]);
        w2.x = pkb(xv[12], xv[13]); w2.y = pkb(xv[15], xv[16]);
        w2.z = pkb(xv[18], xv[19]); w2.w = pkb(xv[21], xv[22]);
        *(uint4*)&XQ[k0]     = w1;
        *(uint4*)&XQ[k0 + 4] = w2;
        // VT4 rows d=0..2 (natural key order), d=3 ones
#pragma unroll
        for (int d = 0; d < 3; ++d) {
            uint4 w;
            w.x = pkb(xv[0 + d],  xv[3 + d]);
            w.y = pkb(xv[6 + d],  xv[9 + d]);
            w.z = pkb(xv[12 + d], xv[15 + d]);
            w.w = pkb(xv[18 + d], xv[21 + d]);
            *(uint4*)(VT4 + kt * 128 + d * 32 + c0 * 2) = w;
        }
        uint4 ones; ones.x = ones.y = ones.z = ones.w = 0x3F803F80u;
        *(uint4*)(VT4 + kt * 128 + 3 * 32 + c0 * 2) = ones;
    }

    // per-head weights (wave-uniform h -> scalar loads)
    const float* wqp = Wq + h * 9;
    const float* wkp = Wk + h * 9;
    const float* wvp = Wv + h * 9;
    float wq_[9], wk_[9], wv_[9];
#pragma unroll
    for (int i = 0; i < 9; ++i) { wq_[i] = wqp[i]; wk_[i] = wkp[i]; wv_[i] = wvp[i]; }

    const int lane = tid & 63;
    const int wid  = tid >> 6;    // k-split: 512 keys per wave
    const int ql   = lane & 31;
    const int q    = qb * 32 + ql;

    // u = (x_q Wq) Wk^T * scale * log2(e) from f32 x (global, L2-hot)
    const float* gq = x + b * SEQ * 3 + q * 3;
    const float xq0 = gq[0], xq1 = gq[1], xq2 = gq[2];
    const float Q0 = xq0 * wq_[0] + xq1 * wq_[3] + xq2 * wq_[6];
    const float Q1 = xq0 * wq_[1] + xq1 * wq_[4] + xq2 * wq_[7];
    const float Q2 = xq0 * wq_[2] + xq1 * wq_[5] + xq2 * wq_[8];
    const float cc = 0.5773502691896258f * 1.4426950408889634f;
    const float u0 = (Q0 * wk_[0] + Q1 * wk_[1] + Q2 * wk_[2]) * cc;
    const float u1 = (Q0 * wk_[3] + Q1 * wk_[4] + Q2 * wk_[5]) * cc;
    const float u2 = (Q0 * wk_[6] + Q1 * wk_[7] + Q2 * wk_[8]) * cc;

    __syncthreads();

    // scores-mfma B operand: B[k, col=q]; lanes>=32 (k=8..15) zero
    UBv Bs;
    Bs.u[0] = (lane < 32) ? pkb(u0, u1) : 0u;
    Bs.u[1] = (lane < 32) ? pkb(u2, 0.f) : 0u;
    Bs.u[2] = 0u; Bs.u[3] = 0u;

    // per-wave addresses
    const int   kbase = wid * 512;
    const u32*  xqp   = &XQ[kbase + ql];                                     // A word0
    const char* x2a   = VT4 + wid * 4096 + ((lane >> 4) & 1) * 128 + 64 + (lane & 15) * 2;  // A word1 (u16)
    const char* vb    = VT4 + wid * 4096 + (lane & 3) * 32 + (lane >> 5) * 8;               // PV-B base

    f32x16_t pvC = {};  // C[row=q', col: 0..3 = {a0,a1,a2,l}]
    f32x16_t zc  = {};

    // ---- software-pipelined main loop: 16 k-tiles of 32 keys per wave ----
    // prologue: tile 0 A-frag + scores-MFMA
    UBv Af;
    Af.u[0] = xqp[0];
    Af.u[1] = (u32)*(const unsigned short*)(x2a);
    Af.u[2] = 0u; Af.u[3] = 0u;
    f32x16_t sc = __builtin_amdgcn_mfma_f32_32x32x16_bf16(Af.v, Bs.v, zc, 0, 0, 0);

#pragma unroll
    for (int t = 0; t < 16; ++t) {
        // B-frag loads for tile t (consumed by PV ~150 cyc later)
        const uint2 b0a = *(const uint2*)(vb + t * 256 + 0);
        const uint2 b0b = *(const uint2*)(vb + t * 256 + 16);
        const uint2 b1a = *(const uint2*)(vb + t * 256 + 128);
        const uint2 b1b = *(const uint2*)(vb + t * 256 + 144);
        // A prefetch for tile t+1
        u32 nA0 = 0u, nA1 = 0u;
        if (t < 15) {
            nA0 = xqp[(t + 1) * 32];
            nA1 = (u32)*(const unsigned short*)(x2a + (t + 1) * 256);
        }

        // exp + pack of tile t scores (covers the B-load and A-prefetch latency)
        UBv PA;
        PA.u[0] = pkb(exp2_fast(sc[0]), exp2_fast(sc[1]));
        PA.u[1] = pkb(exp2_fast(sc[2]), exp2_fast(sc[3]));
        PA.u[2] = pkb(exp2_fast(sc[4]), exp2_fast(sc[5]));
        PA.u[3] = pkb(exp2_fast(sc[6]), exp2_fast(sc[7]));
        UBv PB;
        PB.u[0] = pkb(exp2_fast(sc[8]),  exp2_fast(sc[9]));
        PB.u[1] = pkb(exp2_fast(sc[10]), exp2_fast(sc[11]));
        PB.u[2] = pkb(exp2_fast(sc[12]), exp2_fast(sc[13]));
        PB.u[3] = pkb(exp2_fast(sc[14]), exp2_fast(sc[15]));

        // PV MFMAs for tile t
        UBv B0; B0.u[0] = b0a.x; B0.u[1] = b0a.y; B0.u[2] = b0b.x; B0.u[3] = b0b.y;
        pvC = __builtin_amdgcn_mfma_f32_32x32x16_bf16(PA.v, B0.v, pvC, 0, 0, 0);
        UBv B1; B1.u[0] = b1a.x; B1.u[1] = b1a.y; B1.u[2] = b1b.x; B1.u[3] = b1b.y;
        pvC = __builtin_amdgcn_mfma_f32_32x32x16_bf16(PB.v, B1.v, pvC, 0, 0, 0);

        // scores-MFMA for tile t+1 (result needed at top of next iteration)
        if (t < 15) {
            Af.u[0] = nA0; Af.u[1] = nA1;
            sc = __builtin_amdgcn_mfma_f32_32x32x16_bf16(Af.v, Bs.v, zc, 0, 0, 0);
        }
    }

    // ---- merge 4 k-splits + epilogue ----
    const int d31 = lane & 31;
    if (d31 < 4) {
        const int slot = ((lane >> 5) << 2) | d31;
#pragma unroll
        for (int i = 0; i < 4; ++i) {
            float4 w; w.x = pvC[i * 4 + 0]; w.y = pvC[i * 4 + 1];
            w.z = pvC[i * 4 + 2]; w.w = pvC[i * 4 + 3];
            *(float4*)&RED[wid][slot][i * 4] = w;
        }
    }
    __syncthreads();

    if (wid == 0 && lane < 32) {
        const int qrow = lane;
        const int hh2 = (qrow >> 2) & 1;
        const int r   = (qrow & 3) | ((qrow >> 3) << 2);
        float acc[4];
#pragma unroll
        for (int d = 0; d < 4; ++d)
            acc[d] = (RED[0][hh2 * 4 + d][r] + RED[1][hh2 * 4 + d][r])
                   + (RED[2][hh2 * 4 + d][r] + RED[3][hh2 * 4 + d][r]);
        const float inv = 1.0f / fmaxf(acc[3], 1e-37f);
        const float r0 = acc[0] * inv, r1 = acc[1] * inv, r2 = acc[2] * inv;
        const float o0 = r0 * wv_[0] + r1 * wv_[3] + r2 * wv_[6];
        const float o1 = r0 * wv_[1] + r1 * wv_[4] + r2 * wv_[7];
        const float o2 = r0 * wv_[2] + r1 * wv_[5] + r2 * wv_[8];
        const int qg = qb * 32 + qrow;
        const int o  = bh * (SEQ * 3) + qg * 3;
        const int second = NB * NH * SEQ * 3;
        out[o + 0] = o0; out[o + 1] = o1; out[o + 2] = o2;
        out[o + second + 0] = o0; out[o + second + 1] = o1; out[o + second + 2] = o2;
    }
}

extern "C" void kernel_launch(void* const* d_in, const int* in_sizes, int n_in,
                              void* d_out, int out_size, void* d_ws, size_t ws_size,
                              hipStream_t stream) {
    const float* x  = (const float*)d_in[0];
    const float* Wq = (const float*)d_in[1];
    const float* Wk = (const float*)d_in[2];
    const float* Wv = (const float*)d_in[3];
    float* out = (float*)d_out;
    (void)in_sizes; (void)n_in; (void)d_ws; (void)ws_size; (void)out_size;

    const int grid = NB * NH * (SEQ / 32);  // 2048 blocks
    attn_mfma<<<grid, 256, 0, stream>>>(x, Wq, Wk, Wv, out);
}